// Round 8
// baseline (262.466 us; speedup 1.0000x reference)
//
#include <hip/hip_runtime.h>

// MHA forward: B=4, S=2048, D=768, H=12, Hd=64
// prep (cvt x + transpose weights) -> qkv GEMM (dbuf) -> flash attn
// (swapped-QK, in-reg softmax, barrier-free, K/V direct from L2 with
// permuted-K addressing) -> proj GEMM.

typedef _Float16 f16;
typedef _Float16 f16x8 __attribute__((ext_vector_type(8)));
typedef _Float16 f16x4 __attribute__((ext_vector_type(4)));
typedef float f32x4 __attribute__((ext_vector_type(4)));

#define BQ 4
#define SQ 2048
#define DQ 768
#define HQ 12
#define HD 64
#define M_TOK (BQ*SQ)      // 8192
#define KVB 64
#define NT (SQ/KVB)         // 32 KV tiles
#define QSCALE 0.18033688f  // 0.125 * log2(e): scores land in exp2 domain
#define THR_LOG2 11.5f      // defer-max threshold (~e^8)

__device__ __forceinline__ void gld_lds16(const f16* g, f16* l) {
  __builtin_amdgcn_global_load_lds((const __attribute__((address_space(1))) void*)g,
                                   (__attribute__((address_space(3))) void*)l,
                                   16, 0, 0);
}

// ---- prep: cvt x (blocks 0..6143), transpose w_qkv (6144..7871), w_proj (7872..8447)
__global__ __launch_bounds__(256)
void prep(const float* __restrict__ x, f16* __restrict__ xh,
          const float* __restrict__ w_qkv, f16* __restrict__ wqkvT,
          const float* __restrict__ w_proj, f16* __restrict__ wprojT)
{
  __shared__ float tile[32][33];
  const int bid = blockIdx.x, tid = threadIdx.x;
  if (bid < 6144) {
    int i = (bid * 256 + tid) * 4;
    float4 v = *(const float4*)(x + i);
    f16x4 o = { (f16)v.x, (f16)v.y, (f16)v.z, (f16)v.w };
    *(f16x4*)(xh + i) = o;
    return;
  }
  const float* w; f16* wt; int K, N, nb, kb;
  if (bid < 7872) {
    int b2 = bid - 6144; w = w_qkv; wt = wqkvT; K = DQ; N = 3 * DQ;
    nb = (b2 % 72) * 32; kb = (b2 / 72) * 32;
  } else {
    int b3 = bid - 7872; w = w_proj; wt = wprojT; K = DQ; N = DQ;
    nb = (b3 % 24) * 32; kb = (b3 / 24) * 32;
  }
  int tx = tid & 31, ty = tid >> 5;
  for (int r = ty; r < 32; r += 8)
    tile[r][tx] = w[(size_t)(kb + r) * N + nb + tx];
  __syncthreads();
  for (int r = ty; r < 32; r += 8)
    wt[(size_t)(nb + r) * K + kb + tx] = (f16)tile[tx][r];
}

// ---- 128x128 tile GEMM, A [M][K] f16, Bt [N][K] f16, BK=32, double-buffered ----
// MODE 0: qkv epilogue (bias + scatter Q*QSCALE, K, V^T)
// MODE 1: proj epilogue (bias + f32 out)
template<int MODE>
__global__ __launch_bounds__(256, 2)
void gemm128(const f16* __restrict__ A, const f16* __restrict__ Bt,
             const float* __restrict__ bias, float* __restrict__ Cf,
             f16* __restrict__ Qb, f16* __restrict__ Kb, f16* __restrict__ Vt,
             int M, int N, int K, int nbx)
{
  __shared__ f16 Ash[2][128 * 32];   // 2 x 8 KB
  __shared__ f16 Bsh[2][128 * 32];
  const int tid = threadIdx.x;
  const int bid = blockIdx.x;
  const int nb = bid % nbx, mb = bid / nbx;
  const int m0 = mb * 128, n0 = nb * 128;
  const int lane = tid & 63, wid = tid >> 6;
  const int wr = wid >> 1, wc = wid & 1;
  const int l16 = lane & 15, l4 = lane >> 4;

  f32x4 acc[4][4] = {};

  const int f0 = tid, f1 = tid + 256;
  const f16* a0 = A + (size_t)(m0 + (f0 >> 2)) * K + (f0 & 3) * 8;
  const f16* a1 = A + (size_t)(m0 + (f1 >> 2)) * K + (f1 & 3) * 8;
  const f16* b0 = Bt + (size_t)(n0 + (f0 >> 2)) * K + (f0 & 3) * 8;
  const f16* b1 = Bt + (size_t)(n0 + (f1 >> 2)) * K + (f1 & 3) * 8;

#define GSTAGE(buf, k0)                                   \
  do {                                                    \
    gld_lds16(a0 + (k0), Ash[buf] + f0 * 8);              \
    gld_lds16(a1 + (k0), Ash[buf] + f1 * 8);              \
    gld_lds16(b0 + (k0), Bsh[buf] + f0 * 8);              \
    gld_lds16(b1 + (k0), Bsh[buf] + f1 * 8);              \
  } while (0)

  GSTAGE(0, 0);
  __syncthreads();                      // drains vmcnt: buf0 ready
  for (int k0 = 0; k0 < K; k0 += 32) {
    const int buf = (k0 >> 5) & 1;
    if (k0 + 32 < K) GSTAGE(buf ^ 1, k0 + 32);   // prefetch hides under compute
    f16x8 af[4], bfr[4];
    #pragma unroll
    for (int m = 0; m < 4; ++m)
      af[m] = *(const f16x8*)(Ash[buf] + (wr * 64 + m * 16 + l16) * 32 + l4 * 8);
    #pragma unroll
    for (int n = 0; n < 4; ++n)
      bfr[n] = *(const f16x8*)(Bsh[buf] + (wc * 64 + n * 16 + l16) * 32 + l4 * 8);
    #pragma unroll
    for (int m = 0; m < 4; ++m)
      #pragma unroll
      for (int n = 0; n < 4; ++n)
        acc[m][n] = __builtin_amdgcn_mfma_f32_16x16x32_f16(af[m], bfr[n], acc[m][n], 0, 0, 0);
    __syncthreads();                    // one barrier/iter
  }
#undef GSTAGE

  const int cbase = n0 + wc * 64;
  const int rbase = m0 + wr * 64;
  if (MODE == 1) {
    #pragma unroll
    for (int n = 0; n < 4; ++n) {
      int c = cbase + n * 16 + l16;
      float bv = bias[c];
      #pragma unroll
      for (int m = 0; m < 4; ++m)
        #pragma unroll
        for (int r = 0; r < 4; ++r) {
          int rr = rbase + m * 16 + l4 * 4 + r;
          Cf[(size_t)rr * N + c] = acc[m][n][r] + bv;
        }
    }
  } else {
    #pragma unroll
    for (int n = 0; n < 4; ++n) {
      int c = cbase + n * 16 + l16;
      float bv = bias[c];
      int which = c / DQ;
      int rem = c - which * DQ;
      int h = rem >> 6, hd = rem & 63;
      #pragma unroll
      for (int m = 0; m < 4; ++m) {
        int rr0 = rbase + m * 16 + l4 * 4;          // 4 consecutive tokens, same b
        int b = rr0 >> 11, s = rr0 & 2047;
        size_t bh = (size_t)(b * HQ + h);
        if (which == 2) {
          f16x4 ov = { (f16)(acc[m][n][0] + bv), (f16)(acc[m][n][1] + bv),
                       (f16)(acc[m][n][2] + bv), (f16)(acc[m][n][3] + bv) };
          *(f16x4*)(Vt + (bh * HD + hd) * SQ + s) = ov;
        } else if (which == 0) {
          #pragma unroll
          for (int r = 0; r < 4; ++r)
            Qb[(bh * SQ + s + r) * HD + hd] = (f16)((acc[m][n][r] + bv) * QSCALE);
        } else {
          #pragma unroll
          for (int r = 0; r < 4; ++r)
            Kb[(bh * SQ + s + r) * HD + hd] = (f16)(acc[m][n][r] + bv);
        }
      }
    }
  }
}

// K-row permutation: A-operand row position p reads global K row t0+permK(p).
// Maps C-slot (n,l4,r) [p = n*16+l4*4+r] onto B-slot k = (n&1)*32+l4*8+(n>>1)*4+r,
// so P feeds PV's B-operand directly and V is consumed linearly.
__device__ __forceinline__ int permK(int p) {
  return ((p & 16) << 1) | (((p >> 2) & 3) << 3) | ((p & 32) >> 3) | (p & 3);
}

// ---- flash attention v6: barrier-free, no LDS. K/V fragments read directly
// from global (L2-resident: 512 KB/head, 6 heads/XCD via swizzle -> 3 MB < 4 MB L2).
// Per tile: issue V loads -> QKT -> issue next K loads -> softmax -> PV.
__global__ __launch_bounds__(256, 3)
void attn(const f16* __restrict__ Qb, const f16* __restrict__ Kb,
          const f16* __restrict__ Vt, f16* __restrict__ O)
{
  const int tid = threadIdx.x, lane = tid & 63, wid = tid >> 6;
  const int l16 = lane & 15, l4 = lane >> 4;

  const int nwg = gridDim.x;
  const int cpx = nwg >> 3;
  const int swz = (blockIdx.x & 7) * cpx + (blockIdx.x >> 3);
  const int qt = swz & 15, bh = swz >> 4;
  const int b = bh / HQ, h = bh - b * HQ;
  const f16* q  = Qb + (size_t)bh * SQ * HD;
  const f16* kp = Kb + (size_t)bh * SQ * HD;
  const f16* vp = Vt + (size_t)bh * HD * SQ;
  const int s0 = qt * 128 + wid * 32;

  // Q fragments (B-operand): [group][kk]
  f16x8 qf[2][2];
  #pragma unroll
  for (int g = 0; g < 2; ++g)
    #pragma unroll
    for (int kk = 0; kk < 2; ++kk)
      qf[g][kk] = *(const f16x8*)(q + (size_t)(s0 + g * 16 + l16) * HD + kk * 32 + l4 * 8);

  f32x4 oacc[2][4] = {};
  float mrun[2] = { -1e30f, -1e30f }, lrun[2] = { 0.f, 0.f };

  // per-lane fragment base pointers
  const f16* kpl[4];   // permuted K rows, + kk*32 at load, advance t0*HD
  const f16* vpl[4];   // linear V^T rows,  + t0 + kk*32 at load
  #pragma unroll
  for (int n = 0; n < 4; ++n) {
    kpl[n] = kp + (size_t)permK(n * 16 + l16) * HD + l4 * 8;
    vpl[n] = vp + (size_t)(n * 16 + l16) * SQ + l4 * 8;
  }

  f16x8 kf[2][4], vf[2][4];

#define LOADK(t0)                                                             \
  do {                                                                        \
    _Pragma("unroll")                                                         \
    for (int kk = 0; kk < 2; ++kk)                                            \
      _Pragma("unroll")                                                       \
      for (int n = 0; n < 4; ++n)                                             \
        kf[kk][n] = *(const f16x8*)(kpl[n] + (size_t)(t0) * HD + kk * 32);    \
  } while (0)
#define LOADV(t0)                                                             \
  do {                                                                        \
    _Pragma("unroll")                                                         \
    for (int kk = 0; kk < 2; ++kk)                                            \
      _Pragma("unroll")                                                       \
      for (int n = 0; n < 4; ++n)                                             \
        vf[kk][n] = *(const f16x8*)(vpl[n] + (t0) + kk * 32);                 \
  } while (0)

  LOADK(0);
  for (int t = 0; t < NT; ++t) {
    LOADV(t * KVB);                       // consumed after softmax: hidden
    // QKT from current kf
    f32x4 sacc[2][4] = {};
    __builtin_amdgcn_s_setprio(1);
    #pragma unroll
    for (int kk = 0; kk < 2; ++kk)
      #pragma unroll
      for (int n = 0; n < 4; ++n) {
        sacc[0][n] = __builtin_amdgcn_mfma_f32_16x16x32_f16(kf[kk][n], qf[0][kk], sacc[0][n], 0, 0, 0);
        sacc[1][n] = __builtin_amdgcn_mfma_f32_16x16x32_f16(kf[kk][n], qf[1][kk], sacc[1][n], 0, 0, 0);
      }
    __builtin_amdgcn_s_setprio(0);
    if (t + 1 < NT) LOADK((t + 1) * KVB); // hidden under softmax+PV
    // softmax (in-register, 2 shfl rounds, exp2 domain, defer-max)
    f16x8 bfr[2][2];
    #pragma unroll
    for (int g = 0; g < 2; ++g) {
      float rm = -1e30f;
      #pragma unroll
      for (int n = 0; n < 4; ++n)
        rm = fmaxf(rm, fmaxf(fmaxf(sacc[g][n][0], sacc[g][n][1]),
                             fmaxf(sacc[g][n][2], sacc[g][n][3])));
      rm = fmaxf(rm, __shfl_xor(rm, 16));
      rm = fmaxf(rm, __shfl_xor(rm, 32));
      if (!__all(rm - mrun[g] <= THR_LOG2)) {
        float mn = fmaxf(mrun[g], rm);
        float corr = __builtin_amdgcn_exp2f(mrun[g] - mn);
        lrun[g] *= corr;
        #pragma unroll
        for (int n = 0; n < 4; ++n)
          oacc[g][n] *= corr;
        mrun[g] = mn;
      }
      float mref = mrun[g];
      float ps = 0.f;
      #pragma unroll
      for (int n = 0; n < 4; ++n)
        #pragma unroll
        for (int r = 0; r < 4; ++r) {
          float pv = __builtin_amdgcn_exp2f(sacc[g][n][r] - mref);
          bfr[g][n & 1][(n >> 1) * 4 + r] = (f16)pv;
          ps += pv;
        }
      ps += __shfl_xor(ps, 16);
      ps += __shfl_xor(ps, 32);
      lrun[g] += ps;
    }
    // PV from vf
    __builtin_amdgcn_s_setprio(1);
    #pragma unroll
    for (int kk = 0; kk < 2; ++kk)
      #pragma unroll
      for (int n = 0; n < 4; ++n) {
        oacc[0][n] = __builtin_amdgcn_mfma_f32_16x16x32_f16(vf[kk][n], bfr[0][kk], oacc[0][n], 0, 0, 0);
        oacc[1][n] = __builtin_amdgcn_mfma_f32_16x16x32_f16(vf[kk][n], bfr[1][kk], oacc[1][n], 0, 0, 0);
      }
    __builtin_amdgcn_s_setprio(0);
  }
#undef LOADK
#undef LOADV

  #pragma unroll
  for (int g = 0; g < 2; ++g) {
    float inv = 1.f / lrun[g];
    const int s = s0 + g * 16 + l16;
    f16* obase = O + ((size_t)b * SQ + s) * DQ + h * HD + l4 * 4;
    #pragma unroll
    for (int n = 0; n < 4; ++n) {
      f16x4 ov = { (f16)(oacc[g][n][0] * inv), (f16)(oacc[g][n][1] * inv),
                   (f16)(oacc[g][n][2] * inv), (f16)(oacc[g][n][3] * inv) };
      *(f16x4*)(obase + n * 16) = ov;
    }
  }
}

extern "C" void kernel_launch(void* const* d_in, const int* in_sizes, int n_in,
                              void* d_out, int out_size, void* d_ws, size_t ws_size,
                              hipStream_t stream) {
  const float* x      = (const float*)d_in[0];
  const float* w_qkv  = (const float*)d_in[1];
  const float* b_qkv  = (const float*)d_in[2];
  const float* w_proj = (const float*)d_in[3];
  const float* b_proj = (const float*)d_in[4];
  float* out = (float*)d_out;

  char* ws = (char*)d_ws;
  f16* xh     = (f16*)ws; ws += (size_t)M_TOK * DQ * 2;
  f16* wqkvT  = (f16*)ws; ws += (size_t)3 * DQ * DQ * 2;
  f16* wprojT = (f16*)ws; ws += (size_t)DQ * DQ * 2;
  f16* Qb     = (f16*)ws; ws += (size_t)M_TOK * DQ * 2;
  f16* Kb     = (f16*)ws; ws += (size_t)M_TOK * DQ * 2;
  f16* Vt     = (f16*)ws; ws += (size_t)M_TOK * DQ * 2;
  f16* AO     = xh;  // attn output; xh fully consumed by qkv GEMM before attn

  prep<<<8448, 256, 0, stream>>>(x, xh, w_qkv, wqkvT, w_proj, wprojT);

  gemm128<0><<<(M_TOK / 128) * (3 * DQ / 128), 256, 0, stream>>>(
      xh, wqkvT, b_qkv, nullptr, Qb, Kb, Vt, M_TOK, 3 * DQ, DQ, 3 * DQ / 128);

  attn<<<BQ * HQ * (SQ / 128), 256, 0, stream>>>(Qb, Kb, Vt, AO);

  gemm128<1><<<(M_TOK / 128) * (DQ / 128), 256, 0, stream>>>(
      AO, wprojT, b_proj, out, nullptr, nullptr, nullptr, M_TOK, DQ, DQ, DQ / 128);
}

// Round 9
// 176.810 us; speedup vs baseline: 1.4845x; 1.4845x over previous
//
#include <hip/hip_runtime.h>

// MHA forward: B=4, S=2048, D=768, H=12, Hd=64
// prep (cvt x + transpose weights) -> qkv GEMM (128x256 tile, 64x128/wave,
// dbuf) -> flash attn (R6: swapped-QK, in-reg softmax, LDS-shared KV, dbuf)
// -> proj GEMM (same 128x256 structure).

typedef _Float16 f16;
typedef _Float16 f16x8 __attribute__((ext_vector_type(8)));
typedef _Float16 f16x4 __attribute__((ext_vector_type(4)));
typedef float f32x4 __attribute__((ext_vector_type(4)));

#define BQ 4
#define SQ 2048
#define DQ 768
#define HQ 12
#define HD 64
#define M_TOK (BQ*SQ)      // 8192
#define KVB 64
#define QSCALE 0.18033688f  // 0.125 * log2(e): scores land in exp2 domain
#define THR_LOG2 11.5f      // defer-max threshold (~e^8)

__device__ __forceinline__ void gld_lds16(const f16* g, f16* l) {
  __builtin_amdgcn_global_load_lds((const __attribute__((address_space(1))) void*)g,
                                   (__attribute__((address_space(3))) void*)l,
                                   16, 0, 0);
}

// ---- prep: cvt x (blocks 0..6143), transpose w_qkv (6144..7871), w_proj (7872..8447)
__global__ __launch_bounds__(256)
void prep(const float* __restrict__ x, f16* __restrict__ xh,
          const float* __restrict__ w_qkv, f16* __restrict__ wqkvT,
          const float* __restrict__ w_proj, f16* __restrict__ wprojT)
{
  __shared__ float tile[32][33];
  const int bid = blockIdx.x, tid = threadIdx.x;
  if (bid < 6144) {
    int i = (bid * 256 + tid) * 4;
    float4 v = *(const float4*)(x + i);
    f16x4 o = { (f16)v.x, (f16)v.y, (f16)v.z, (f16)v.w };
    *(f16x4*)(xh + i) = o;
    return;
  }
  const float* w; f16* wt; int K, N, nb, kb;
  if (bid < 7872) {
    int b2 = bid - 6144; w = w_qkv; wt = wqkvT; K = DQ; N = 3 * DQ;
    nb = (b2 % 72) * 32; kb = (b2 / 72) * 32;
  } else {
    int b3 = bid - 7872; w = w_proj; wt = wprojT; K = DQ; N = DQ;
    nb = (b3 % 24) * 32; kb = (b3 / 24) * 32;
  }
  int tx = tid & 31, ty = tid >> 5;
  for (int r = ty; r < 32; r += 8)
    tile[r][tx] = w[(size_t)(kb + r) * N + nb + tx];
  __syncthreads();
  for (int r = ty; r < 32; r += 8)
    wt[(size_t)(nb + r) * K + kb + tx] = (f16)tile[tx][r];
}

// ---- 128x256 tile GEMM, A [M][K] f16, Bt [N][K] f16, BK=32, dbuf ----
// Wave tile 64x128 (acc[4][8]) -> 29 FLOP/LDS-byte (vs 13 at 128x128).
// MODE 0: qkv epilogue (bias + scatter Q*QSCALE, K, V^T)
// MODE 1: proj epilogue (bias + f32 out)
template<int MODE>
__global__ __launch_bounds__(256, 2)
void gemm256(const f16* __restrict__ A, const f16* __restrict__ Bt,
             const float* __restrict__ bias, float* __restrict__ Cf,
             f16* __restrict__ Qb, f16* __restrict__ Kb, f16* __restrict__ Vt,
             int M, int N, int K, int nbx)
{
  __shared__ f16 Ash[2][128 * 32];   // 2 x 8 KB
  __shared__ f16 Bsh[2][256 * 32];   // 2 x 16 KB
  const int tid = threadIdx.x;
  // bijective XCD swizzle (grid % 8 == 0)
  const int cpx = gridDim.x >> 3;
  const int bid = (blockIdx.x & 7) * cpx + (blockIdx.x >> 3);
  const int nb = bid % nbx, mb = bid / nbx;
  const int m0 = mb * 128, n0 = nb * 256;
  const int lane = tid & 63, wid = tid >> 6;
  const int wr = wid >> 1, wc = wid & 1;
  const int l16 = lane & 15, l4 = lane >> 4;

  f32x4 acc[4][8] = {};

  // staging: A chunks tid, tid+256; B chunks tid + j*256 (j=0..3)
  const f16* aS0 = A + (size_t)(m0 + (tid >> 2)) * K + (tid & 3) * 8;
  const f16* aS1 = A + (size_t)(m0 + ((tid + 256) >> 2)) * K + (tid & 3) * 8;
  const f16* bS0 = Bt + (size_t)(n0 + (tid >> 2)) * K + (tid & 3) * 8;
  const f16* bS1 = bS0 + (size_t)64 * K;
  const f16* bS2 = bS0 + (size_t)128 * K;
  const f16* bS3 = bS0 + (size_t)192 * K;

#define GSTAGE(buf, k0)                                        \
  do {                                                         \
    gld_lds16(aS0 + (k0), Ash[buf] + tid * 8);                 \
    gld_lds16(aS1 + (k0), Ash[buf] + (tid + 256) * 8);         \
    gld_lds16(bS0 + (k0), Bsh[buf] + tid * 8);                 \
    gld_lds16(bS1 + (k0), Bsh[buf] + (tid + 256) * 8);         \
    gld_lds16(bS2 + (k0), Bsh[buf] + (tid + 512) * 8);         \
    gld_lds16(bS3 + (k0), Bsh[buf] + (tid + 768) * 8);         \
  } while (0)

  GSTAGE(0, 0);
  __syncthreads();                      // buf0 ready
  for (int k0 = 0; k0 < K; k0 += 32) {
    const int buf = (k0 >> 5) & 1;
    if (k0 + 32 < K) GSTAGE(buf ^ 1, k0 + 32);   // prefetch hides under compute
    f16x8 af[4], bfr[8];
    #pragma unroll
    for (int m = 0; m < 4; ++m)
      af[m] = *(const f16x8*)(Ash[buf] + (wr * 64 + m * 16 + l16) * 32 + l4 * 8);
    #pragma unroll
    for (int n = 0; n < 8; ++n)
      bfr[n] = *(const f16x8*)(Bsh[buf] + (wc * 128 + n * 16 + l16) * 32 + l4 * 8);
    #pragma unroll
    for (int m = 0; m < 4; ++m)
      #pragma unroll
      for (int n = 0; n < 8; ++n)
        acc[m][n] = __builtin_amdgcn_mfma_f32_16x16x32_f16(af[m], bfr[n], acc[m][n], 0, 0, 0);
    __syncthreads();                    // one barrier/iter
  }
#undef GSTAGE

  const int cbase = n0 + wc * 128;
  const int rbase = m0 + wr * 64;
  if (MODE == 1) {
    #pragma unroll
    for (int n = 0; n < 8; ++n) {
      int c = cbase + n * 16 + l16;
      float bv = bias[c];
      #pragma unroll
      for (int m = 0; m < 4; ++m)
        #pragma unroll
        for (int r = 0; r < 4; ++r) {
          int rr = rbase + m * 16 + l4 * 4 + r;
          Cf[(size_t)rr * N + c] = acc[m][n][r] + bv;
        }
    }
  } else {
    #pragma unroll
    for (int n = 0; n < 8; ++n) {
      int c = cbase + n * 16 + l16;
      float bv = bias[c];
      int which = c / DQ;
      int rem = c - which * DQ;
      int h = rem >> 6, hd = rem & 63;
      #pragma unroll
      for (int m = 0; m < 4; ++m) {
        int rr0 = rbase + m * 16 + l4 * 4;          // 4 consecutive tokens, same b
        int b = rr0 >> 11, s = rr0 & 2047;
        size_t bh = (size_t)(b * HQ + h);
        if (which == 2) {
          f16x4 ov = { (f16)(acc[m][n][0] + bv), (f16)(acc[m][n][1] + bv),
                       (f16)(acc[m][n][2] + bv), (f16)(acc[m][n][3] + bv) };
          *(f16x4*)(Vt + (bh * HD + hd) * SQ + s) = ov;
        } else if (which == 0) {
          #pragma unroll
          for (int r = 0; r < 4; ++r)
            Qb[(bh * SQ + s + r) * HD + hd] = (f16)((acc[m][n][r] + bv) * QSCALE);
        } else {
          #pragma unroll
          for (int r = 0; r < 4; ++r)
            Kb[(bh * SQ + s + r) * HD + hd] = (f16)(acc[m][n][r] + bv);
        }
      }
    }
  }
}

// K-row permutation: LDS row p holds global K row t0+perm(p).
// Maps C-slot (n,l4,r) [t_lds = n*16+l4*4+r] onto B-slot k = (n&1)*32+l4*8+(n>>1)*4+r.
__device__ __forceinline__ int permK(int p) {
  return ((p & 16) << 1) | (((p >> 2) & 3) << 3) | ((p & 32) >> 3) | (p & 3);
}

// ---- flash attention (R6 known-good: 82 us) ----
__global__ __launch_bounds__(256, 3)
void attn(const f16* __restrict__ Qb, const f16* __restrict__ Kb,
          const f16* __restrict__ Vt, f16* __restrict__ O)
{
  __shared__ f16 Ksh[2][KVB * HD];
  __shared__ f16 Vsh[2][HD * KVB];
  const int tid = threadIdx.x, lane = tid & 63, wid = tid >> 6;
  const int l16 = lane & 15, l4 = lane >> 4;

  const int nwg = gridDim.x;
  const int cpx = nwg >> 3;
  const int swz = (blockIdx.x & 7) * cpx + (blockIdx.x >> 3);
  const int qt = swz & 15, bh = swz >> 4;
  const int b = bh / HQ, h = bh - b * HQ;
  const f16* q  = Qb + (size_t)bh * SQ * HD;
  const f16* kp = Kb + (size_t)bh * SQ * HD;
  const f16* vp = Vt + (size_t)bh * HD * SQ;
  const int s0 = qt * 128 + wid * 32;

  f16x8 qf[2][2];
  #pragma unroll
  for (int g = 0; g < 2; ++g)
    #pragma unroll
    for (int kk = 0; kk < 2; ++kk)
      qf[g][kk] = *(const f16x8*)(q + (size_t)(s0 + g * 16 + l16) * HD + kk * 32 + l4 * 8);

  f32x4 oacc[2][4] = {};
  float mrun[2] = { -1e30f, -1e30f }, lrun[2] = { 0.f, 0.f };

  const int p0 = tid >> 3, p1 = (tid >> 3) + 32;
  const int scS = ((tid & 7) ^ (p0 & 7)) * 8;
  const int kr0 = permK(p0), kr1 = permK(p1);

#define STAGE(buf, t0)                                                        \
  do {                                                                        \
    gld_lds16(kp + (size_t)((t0) + kr0) * HD + scS, Ksh[buf] + tid * 8);      \
    gld_lds16(kp + (size_t)((t0) + kr1) * HD + scS, Ksh[buf] + (tid + 256) * 8);\
    gld_lds16(vp + (size_t)p0 * SQ + (t0) + scS,   Vsh[buf] + tid * 8);       \
    gld_lds16(vp + (size_t)p1 * SQ + (t0) + scS,   Vsh[buf] + (tid + 256) * 8);\
  } while (0)

#define COMPUTE(buf)                                                          \
  do {                                                                        \
    f32x4 sacc[2][4] = {};                                                    \
    __builtin_amdgcn_s_setprio(1);                                            \
    _Pragma("unroll")                                                         \
    for (int kk = 0; kk < 2; ++kk) {                                          \
      f16x8 kf[4];                                                            \
      _Pragma("unroll")                                                       \
      for (int n = 0; n < 4; ++n)                                             \
        kf[n] = *(const f16x8*)(Ksh[buf] + (n * 16 + l16) * HD +              \
                                ((kk * 32 + l4 * 8) ^ ((l16 & 7) * 8)));      \
      _Pragma("unroll")                                                       \
      for (int n = 0; n < 4; ++n) {                                           \
        sacc[0][n] = __builtin_amdgcn_mfma_f32_16x16x32_f16(kf[n], qf[0][kk], sacc[0][n], 0, 0, 0); \
        sacc[1][n] = __builtin_amdgcn_mfma_f32_16x16x32_f16(kf[n], qf[1][kk], sacc[1][n], 0, 0, 0); \
      }                                                                       \
    }                                                                         \
    __builtin_amdgcn_s_setprio(0);                                            \
    f16x8 bfr[2][2];                                                          \
    _Pragma("unroll")                                                         \
    for (int g = 0; g < 2; ++g) {                                             \
      float rm = -1e30f;                                                      \
      _Pragma("unroll")                                                       \
      for (int n = 0; n < 4; ++n)                                             \
        rm = fmaxf(rm, fmaxf(fmaxf(sacc[g][n][0], sacc[g][n][1]),             \
                             fmaxf(sacc[g][n][2], sacc[g][n][3])));           \
      rm = fmaxf(rm, __shfl_xor(rm, 16));                                     \
      rm = fmaxf(rm, __shfl_xor(rm, 32));                                     \
      if (!__all(rm - mrun[g] <= THR_LOG2)) {                                 \
        float mn = fmaxf(mrun[g], rm);                                        \
        float corr = __builtin_amdgcn_exp2f(mrun[g] - mn);                    \
        lrun[g] *= corr;                                                      \
        _Pragma("unroll")                                                     \
        for (int n = 0; n < 4; ++n)                                           \
          oacc[g][n] *= corr;                                                 \
        mrun[g] = mn;                                                         \
      }                                                                       \
      float mref = mrun[g];                                                   \
      float ps = 0.f;                                                         \
      _Pragma("unroll")                                                       \
      for (int n = 0; n < 4; ++n)                                             \
        _Pragma("unroll")                                                     \
        for (int r = 0; r < 4; ++r) {                                         \
          float pv = __builtin_amdgcn_exp2f(sacc[g][n][r] - mref);            \
          bfr[g][n & 1][(n >> 1) * 4 + r] = (f16)pv;                          \
          ps += pv;                                                           \
        }                                                                     \
      ps += __shfl_xor(ps, 16);                                               \
      ps += __shfl_xor(ps, 32);                                               \
      lrun[g] += ps;                                                          \
    }                                                                         \
    __builtin_amdgcn_s_setprio(1);                                            \
    _Pragma("unroll")                                                         \
    for (int kk = 0; kk < 2; ++kk) {                                          \
      f16x8 vf[4];                                                            \
      _Pragma("unroll")                                                       \
      for (int n = 0; n < 4; ++n)                                             \
        vf[n] = *(const f16x8*)(Vsh[buf] + (n * 16 + l16) * KVB +             \
                                ((kk * 32 + l4 * 8) ^ ((l16 & 7) * 8)));      \
      _Pragma("unroll")                                                       \
      for (int n = 0; n < 4; ++n) {                                           \
        oacc[0][n] = __builtin_amdgcn_mfma_f32_16x16x32_f16(vf[n], bfr[0][kk], oacc[0][n], 0, 0, 0); \
        oacc[1][n] = __builtin_amdgcn_mfma_f32_16x16x32_f16(vf[n], bfr[1][kk], oacc[1][n], 0, 0, 0); \
      }                                                                       \
    }                                                                         \
    __builtin_amdgcn_s_setprio(0);                                            \
  } while (0)

  STAGE(0, 0);
  __syncthreads();
  for (int t0 = 0; t0 < SQ; t0 += 2 * KVB) {
    STAGE(1, t0 + KVB);
    COMPUTE(0);
    __syncthreads();
    if (t0 + 2 * KVB < SQ) STAGE(0, t0 + 2 * KVB);
    COMPUTE(1);
    __syncthreads();
  }
#undef STAGE
#undef COMPUTE

  #pragma unroll
  for (int g = 0; g < 2; ++g) {
    float inv = 1.f / lrun[g];
    const int s = s0 + g * 16 + l16;
    f16* obase = O + ((size_t)b * SQ + s) * DQ + h * HD + l4 * 4;
    #pragma unroll
    for (int n = 0; n < 4; ++n) {
      f16x4 ov = { (f16)(oacc[g][n][0] * inv), (f16)(oacc[g][n][1] * inv),
                   (f16)(oacc[g][n][2] * inv), (f16)(oacc[g][n][3] * inv) };
      *(f16x4*)(obase + n * 16) = ov;
    }
  }
}

extern "C" void kernel_launch(void* const* d_in, const int* in_sizes, int n_in,
                              void* d_out, int out_size, void* d_ws, size_t ws_size,
                              hipStream_t stream) {
  const float* x      = (const float*)d_in[0];
  const float* w_qkv  = (const float*)d_in[1];
  const float* b_qkv  = (const float*)d_in[2];
  const float* w_proj = (const float*)d_in[3];
  const float* b_proj = (const float*)d_in[4];
  float* out = (float*)d_out;

  char* ws = (char*)d_ws;
  f16* xh     = (f16*)ws; ws += (size_t)M_TOK * DQ * 2;
  f16* wqkvT  = (f16*)ws; ws += (size_t)3 * DQ * DQ * 2;
  f16* wprojT = (f16*)ws; ws += (size_t)DQ * DQ * 2;
  f16* Qb     = (f16*)ws; ws += (size_t)M_TOK * DQ * 2;
  f16* Kb     = (f16*)ws; ws += (size_t)M_TOK * DQ * 2;
  f16* Vt     = (f16*)ws; ws += (size_t)M_TOK * DQ * 2;
  f16* AO     = xh;  // attn output; xh fully consumed by qkv GEMM before attn

  prep<<<8448, 256, 0, stream>>>(x, xh, w_qkv, wqkvT, w_proj, wprojT);

  gemm256<0><<<(M_TOK / 128) * (3 * DQ / 256), 256, 0, stream>>>(
      xh, wqkvT, b_qkv, nullptr, Qb, Kb, Vt, M_TOK, 3 * DQ, DQ, 3 * DQ / 256);

  attn<<<BQ * HQ * (SQ / 128), 256, 0, stream>>>(Qb, Kb, Vt, AO);

  gemm256<1><<<(M_TOK / 128) * (DQ / 256), 256, 0, stream>>>(
      AO, wprojT, b_proj, out, nullptr, nullptr, nullptr, M_TOK, DQ, DQ, DQ / 256);
}

// Round 10
// 159.980 us; speedup vs baseline: 1.6406x; 1.1052x over previous
//
#include <hip/hip_runtime.h>

// MHA forward: B=4, S=2048, D=768, H=12, Hd=64
// prep (cvt x + transpose weights) -> qkv GEMM (128x128 dbuf, BK=64,
// XOR-swizzled LDS: conflict-free ds_read_b128) -> flash attn (R6 known-good)
// -> proj GEMM (same structure).

typedef _Float16 f16;
typedef _Float16 f16x8 __attribute__((ext_vector_type(8)));
typedef _Float16 f16x4 __attribute__((ext_vector_type(4)));
typedef float f32x4 __attribute__((ext_vector_type(4)));

#define BQ 4
#define SQ 2048
#define DQ 768
#define HQ 12
#define HD 64
#define M_TOK (BQ*SQ)      // 8192
#define KVB 64
#define QSCALE 0.18033688f  // 0.125 * log2(e): scores land in exp2 domain
#define THR_LOG2 11.5f      // defer-max threshold (~e^8)

__device__ __forceinline__ void gld_lds16(const f16* g, f16* l) {
  __builtin_amdgcn_global_load_lds((const __attribute__((address_space(1))) void*)g,
                                   (__attribute__((address_space(3))) void*)l,
                                   16, 0, 0);
}

// ---- prep: cvt x (blocks 0..6143), transpose w_qkv (6144..7871), w_proj (7872..8447)
__global__ __launch_bounds__(256)
void prep(const float* __restrict__ x, f16* __restrict__ xh,
          const float* __restrict__ w_qkv, f16* __restrict__ wqkvT,
          const float* __restrict__ w_proj, f16* __restrict__ wprojT)
{
  __shared__ float tile[32][33];
  const int bid = blockIdx.x, tid = threadIdx.x;
  if (bid < 6144) {
    int i = (bid * 256 + tid) * 4;
    float4 v = *(const float4*)(x + i);
    f16x4 o = { (f16)v.x, (f16)v.y, (f16)v.z, (f16)v.w };
    *(f16x4*)(xh + i) = o;
    return;
  }
  const float* w; f16* wt; int K, N, nb, kb;
  if (bid < 7872) {
    int b2 = bid - 6144; w = w_qkv; wt = wqkvT; K = DQ; N = 3 * DQ;
    nb = (b2 % 72) * 32; kb = (b2 / 72) * 32;
  } else {
    int b3 = bid - 7872; w = w_proj; wt = wprojT; K = DQ; N = DQ;
    nb = (b3 % 24) * 32; kb = (b3 / 24) * 32;
  }
  int tx = tid & 31, ty = tid >> 5;
  for (int r = ty; r < 32; r += 8)
    tile[r][tx] = w[(size_t)(kb + r) * N + nb + tx];
  __syncthreads();
  for (int r = ty; r < 32; r += 8)
    wt[(size_t)(nb + r) * K + kb + tx] = (f16)tile[tx][r];
}

// ---- 128x128 tile GEMM, A [M][K] f16, Bt [N][K] f16, BK=64, dbuf ----
// LDS rows 128 B (64 f16), chunk-XOR swizzle (row&7) staged via pre-swizzled
// global source; ds_read_b128 conflict-free (attn-proven pattern, 0 conflicts).
// MODE 0: qkv epilogue (bias + scatter Q*QSCALE, K, V^T)
// MODE 1: proj epilogue (bias + f32 out)
template<int MODE>
__global__ __launch_bounds__(256, 2)
void gemm128(const f16* __restrict__ A, const f16* __restrict__ Bt,
             const float* __restrict__ bias, float* __restrict__ Cf,
             f16* __restrict__ Qb, f16* __restrict__ Kb, f16* __restrict__ Vt,
             int M, int N, int K, int nbx)
{
  __shared__ f16 Ash[2][128 * 64];   // 2 x 16 KB
  __shared__ f16 Bsh[2][128 * 64];   // 2 x 16 KB
  const int tid = threadIdx.x;
  const int bid = blockIdx.x;
  const int nb = bid % nbx, mb = bid / nbx;
  const int m0 = mb * 128, n0 = nb * 128;
  const int lane = tid & 63, wid = tid >> 6;
  const int wr = wid >> 1, wc = wid & 1;
  const int l16 = lane & 15, l4 = lane >> 4;

  f32x4 acc[4][4] = {};

  // staging: 1024 16B-chunks per matrix per buffer; thread covers chunks
  // q = j*256+tid (j=0..3). LDS dest linear (q*16 B); global source column
  // pre-XOR'd so LDS slot s of row r holds global chunk s^(r&7).
  const f16* aP[4]; const f16* bP[4]; int lOff[4];
  #pragma unroll
  for (int j = 0; j < 4; ++j) {
    int q = j * 256 + tid;
    int r = q >> 3;
    int sc = ((q & 7) ^ (r & 7)) * 8;     // f16 units
    aP[j] = A  + (size_t)(m0 + r) * K + sc;
    bP[j] = Bt + (size_t)(n0 + r) * K + sc;
    lOff[j] = q * 8;
  }

#define GSTAGE(buf, k0)                                   \
  do {                                                    \
    _Pragma("unroll")                                     \
    for (int j = 0; j < 4; ++j) {                         \
      gld_lds16(aP[j] + (k0), Ash[buf] + lOff[j]);        \
      gld_lds16(bP[j] + (k0), Bsh[buf] + lOff[j]);        \
    }                                                     \
  } while (0)

  GSTAGE(0, 0);
  __syncthreads();                      // buf0 ready
  for (int k0 = 0; k0 < K; k0 += 64) {
    const int buf = (k0 >> 6) & 1;
    if (k0 + 64 < K) GSTAGE(buf ^ 1, k0 + 64);   // prefetch hides under compute
    #pragma unroll
    for (int kk = 0; kk < 2; ++kk) {
      f16x8 af[4], bfr[4];
      #pragma unroll
      for (int m = 0; m < 4; ++m) {
        int R = wr * 64 + m * 16 + l16;
        af[m] = *(const f16x8*)(Ash[buf] + R * 64 + (((kk * 4 + l4) ^ (R & 7)) * 8));
      }
      #pragma unroll
      for (int n = 0; n < 4; ++n) {
        int R = wc * 64 + n * 16 + l16;
        bfr[n] = *(const f16x8*)(Bsh[buf] + R * 64 + (((kk * 4 + l4) ^ (R & 7)) * 8));
      }
      #pragma unroll
      for (int m = 0; m < 4; ++m)
        #pragma unroll
        for (int n = 0; n < 4; ++n)
          acc[m][n] = __builtin_amdgcn_mfma_f32_16x16x32_f16(af[m], bfr[n], acc[m][n], 0, 0, 0);
    }
    __syncthreads();                    // one barrier per 64-K step
  }
#undef GSTAGE

  const int cbase = n0 + wc * 64;
  const int rbase = m0 + wr * 64;
  if (MODE == 1) {
    #pragma unroll
    for (int n = 0; n < 4; ++n) {
      int c = cbase + n * 16 + l16;
      float bv = bias[c];
      #pragma unroll
      for (int m = 0; m < 4; ++m)
        #pragma unroll
        for (int r = 0; r < 4; ++r) {
          int rr = rbase + m * 16 + l4 * 4 + r;
          Cf[(size_t)rr * N + c] = acc[m][n][r] + bv;
        }
    }
  } else {
    #pragma unroll
    for (int n = 0; n < 4; ++n) {
      int c = cbase + n * 16 + l16;
      float bv = bias[c];
      int which = c / DQ;
      int rem = c - which * DQ;
      int h = rem >> 6, hd = rem & 63;
      #pragma unroll
      for (int m = 0; m < 4; ++m) {
        int rr0 = rbase + m * 16 + l4 * 4;          // 4 consecutive tokens, same b
        int b = rr0 >> 11, s = rr0 & 2047;
        size_t bh = (size_t)(b * HQ + h);
        if (which == 2) {
          f16x4 ov = { (f16)(acc[m][n][0] + bv), (f16)(acc[m][n][1] + bv),
                       (f16)(acc[m][n][2] + bv), (f16)(acc[m][n][3] + bv) };
          *(f16x4*)(Vt + (bh * HD + hd) * SQ + s) = ov;
        } else if (which == 0) {
          #pragma unroll
          for (int r = 0; r < 4; ++r)
            Qb[(bh * SQ + s + r) * HD + hd] = (f16)((acc[m][n][r] + bv) * QSCALE);
        } else {
          #pragma unroll
          for (int r = 0; r < 4; ++r)
            Kb[(bh * SQ + s + r) * HD + hd] = (f16)(acc[m][n][r] + bv);
        }
      }
    }
  }
}

// K-row permutation: LDS row p holds global K row t0+perm(p).
// Maps C-slot (n,l4,r) [t_lds = n*16+l4*4+r] onto B-slot k = (n&1)*32+l4*8+(n>>1)*4+r.
__device__ __forceinline__ int permK(int p) {
  return ((p & 16) << 1) | (((p >> 2) & 3) << 3) | ((p & 32) >> 3) | (p & 3);
}

// ---- flash attention (R6 known-good: 82 us) ----
__global__ __launch_bounds__(256, 3)
void attn(const f16* __restrict__ Qb, const f16* __restrict__ Kb,
          const f16* __restrict__ Vt, f16* __restrict__ O)
{
  __shared__ f16 Ksh[2][KVB * HD];
  __shared__ f16 Vsh[2][HD * KVB];
  const int tid = threadIdx.x, lane = tid & 63, wid = tid >> 6;
  const int l16 = lane & 15, l4 = lane >> 4;

  const int nwg = gridDim.x;
  const int cpx = nwg >> 3;
  const int swz = (blockIdx.x & 7) * cpx + (blockIdx.x >> 3);
  const int qt = swz & 15, bh = swz >> 4;
  const int b = bh / HQ, h = bh - b * HQ;
  const f16* q  = Qb + (size_t)bh * SQ * HD;
  const f16* kp = Kb + (size_t)bh * SQ * HD;
  const f16* vp = Vt + (size_t)bh * HD * SQ;
  const int s0 = qt * 128 + wid * 32;

  f16x8 qf[2][2];
  #pragma unroll
  for (int g = 0; g < 2; ++g)
    #pragma unroll
    for (int kk = 0; kk < 2; ++kk)
      qf[g][kk] = *(const f16x8*)(q + (size_t)(s0 + g * 16 + l16) * HD + kk * 32 + l4 * 8);

  f32x4 oacc[2][4] = {};
  float mrun[2] = { -1e30f, -1e30f }, lrun[2] = { 0.f, 0.f };

  const int p0 = tid >> 3, p1 = (tid >> 3) + 32;
  const int scS = ((tid & 7) ^ (p0 & 7)) * 8;
  const int kr0 = permK(p0), kr1 = permK(p1);

#define STAGE(buf, t0)                                                        \
  do {                                                                        \
    gld_lds16(kp + (size_t)((t0) + kr0) * HD + scS, Ksh[buf] + tid * 8);      \
    gld_lds16(kp + (size_t)((t0) + kr1) * HD + scS, Ksh[buf] + (tid + 256) * 8);\
    gld_lds16(vp + (size_t)p0 * SQ + (t0) + scS,   Vsh[buf] + tid * 8);       \
    gld_lds16(vp + (size_t)p1 * SQ + (t0) + scS,   Vsh[buf] + (tid + 256) * 8);\
  } while (0)

#define COMPUTE(buf)                                                          \
  do {                                                                        \
    f32x4 sacc[2][4] = {};                                                    \
    __builtin_amdgcn_s_setprio(1);                                            \
    _Pragma("unroll")                                                         \
    for (int kk = 0; kk < 2; ++kk) {                                          \
      f16x8 kf[4];                                                            \
      _Pragma("unroll")                                                       \
      for (int n = 0; n < 4; ++n)                                             \
        kf[n] = *(const f16x8*)(Ksh[buf] + (n * 16 + l16) * HD +              \
                                ((kk * 32 + l4 * 8) ^ ((l16 & 7) * 8)));      \
      _Pragma("unroll")                                                       \
      for (int n = 0; n < 4; ++n) {                                           \
        sacc[0][n] = __builtin_amdgcn_mfma_f32_16x16x32_f16(kf[n], qf[0][kk], sacc[0][n], 0, 0, 0); \
        sacc[1][n] = __builtin_amdgcn_mfma_f32_16x16x32_f16(kf[n], qf[1][kk], sacc[1][n], 0, 0, 0); \
      }                                                                       \
    }                                                                         \
    __builtin_amdgcn_s_setprio(0);                                            \
    f16x8 bfr[2][2];                                                          \
    _Pragma("unroll")                                                         \
    for (int g = 0; g < 2; ++g) {                                             \
      float rm = -1e30f;                                                      \
      _Pragma("unroll")                                                       \
      for (int n = 0; n < 4; ++n)                                             \
        rm = fmaxf(rm, fmaxf(fmaxf(sacc[g][n][0], sacc[g][n][1]),             \
                             fmaxf(sacc[g][n][2], sacc[g][n][3])));           \
      rm = fmaxf(rm, __shfl_xor(rm, 16));                                     \
      rm = fmaxf(rm, __shfl_xor(rm, 32));                                     \
      if (!__all(rm - mrun[g] <= THR_LOG2)) {                                 \
        float mn = fmaxf(mrun[g], rm);                                        \
        float corr = __builtin_amdgcn_exp2f(mrun[g] - mn);                    \
        lrun[g] *= corr;                                                      \
        _Pragma("unroll")                                                     \
        for (int n = 0; n < 4; ++n)                                           \
          oacc[g][n] *= corr;                                                 \
        mrun[g] = mn;                                                         \
      }                                                                       \
      float mref = mrun[g];                                                   \
      float ps = 0.f;                                                         \
      _Pragma("unroll")                                                       \
      for (int n = 0; n < 4; ++n)                                             \
        _Pragma("unroll")                                                     \
        for (int r = 0; r < 4; ++r) {                                         \
          float pv = __builtin_amdgcn_exp2f(sacc[g][n][r] - mref);            \
          bfr[g][n & 1][(n >> 1) * 4 + r] = (f16)pv;                          \
          ps += pv;                                                           \
        }                                                                     \
      ps += __shfl_xor(ps, 16);                                               \
      ps += __shfl_xor(ps, 32);                                               \
      lrun[g] += ps;                                                          \
    }                                                                         \
    __builtin_amdgcn_s_setprio(1);                                            \
    _Pragma("unroll")                                                         \
    for (int kk = 0; kk < 2; ++kk) {                                          \
      f16x8 vf[4];                                                            \
      _Pragma("unroll")                                                       \
      for (int n = 0; n < 4; ++n)                                             \
        vf[n] = *(const f16x8*)(Vsh[buf] + (n * 16 + l16) * KVB +             \
                                ((kk * 32 + l4 * 8) ^ ((l16 & 7) * 8)));      \
      _Pragma("unroll")                                                       \
      for (int n = 0; n < 4; ++n) {                                           \
        oacc[0][n] = __builtin_amdgcn_mfma_f32_16x16x32_f16(vf[n], bfr[0][kk], oacc[0][n], 0, 0, 0); \
        oacc[1][n] = __builtin_amdgcn_mfma_f32_16x16x32_f16(vf[n], bfr[1][kk], oacc[1][n], 0, 0, 0); \
      }                                                                       \
    }                                                                         \
    __builtin_amdgcn_s_setprio(0);                                            \
  } while (0)

  STAGE(0, 0);
  __syncthreads();
  for (int t0 = 0; t0 < SQ; t0 += 2 * KVB) {
    STAGE(1, t0 + KVB);
    COMPUTE(0);
    __syncthreads();
    if (t0 + 2 * KVB < SQ) STAGE(0, t0 + 2 * KVB);
    COMPUTE(1);
    __syncthreads();
  }
#undef STAGE
#undef COMPUTE

  #pragma unroll
  for (int g = 0; g < 2; ++g) {
    float inv = 1.f / lrun[g];
    const int s = s0 + g * 16 + l16;
    f16* obase = O + ((size_t)b * SQ + s) * DQ + h * HD + l4 * 4;
    #pragma unroll
    for (int n = 0; n < 4; ++n) {
      f16x4 ov = { (f16)(oacc[g][n][0] * inv), (f16)(oacc[g][n][1] * inv),
                   (f16)(oacc[g][n][2] * inv), (f16)(oacc[g][n][3] * inv) };
      *(f16x4*)(obase + n * 16) = ov;
    }
  }
}

extern "C" void kernel_launch(void* const* d_in, const int* in_sizes, int n_in,
                              void* d_out, int out_size, void* d_ws, size_t ws_size,
                              hipStream_t stream) {
  const float* x      = (const float*)d_in[0];
  const float* w_qkv  = (const float*)d_in[1];
  const float* b_qkv  = (const float*)d_in[2];
  const float* w_proj = (const float*)d_in[3];
  const float* b_proj = (const float*)d_in[4];
  float* out = (float*)d_out;

  char* ws = (char*)d_ws;
  f16* xh     = (f16*)ws; ws += (size_t)M_TOK * DQ * 2;
  f16* wqkvT  = (f16*)ws; ws += (size_t)3 * DQ * DQ * 2;
  f16* wprojT = (f16*)ws; ws += (size_t)DQ * DQ * 2;
  f16* Qb     = (f16*)ws; ws += (size_t)M_TOK * DQ * 2;
  f16* Kb     = (f16*)ws; ws += (size_t)M_TOK * DQ * 2;
  f16* Vt     = (f16*)ws; ws += (size_t)M_TOK * DQ * 2;
  f16* AO     = xh;  // attn output; xh fully consumed by qkv GEMM before attn

  prep<<<8448, 256, 0, stream>>>(x, xh, w_qkv, wqkvT, w_proj, wprojT);

  gemm128<0><<<(M_TOK / 128) * (3 * DQ / 128), 256, 0, stream>>>(
      xh, wqkvT, b_qkv, nullptr, Qb, Kb, Vt, M_TOK, 3 * DQ, DQ, 3 * DQ / 128);

  attn<<<BQ * HQ * (SQ / 128), 256, 0, stream>>>(Qb, Kb, Vt, AO);

  gemm128<1><<<(M_TOK / 128) * (DQ / 128), 256, 0, stream>>>(
      AO, wprojT, b_proj, out, nullptr, nullptr, nullptr, M_TOK, DQ, DQ, DQ / 128);
}